// Round 7
// baseline (159.615 us; speedup 1.0000x reference)
//
#include <hip/hip_runtime.h>
#include <hip/hip_bf16.h>
#include <math.h>

// N_MAX_L = [22,19,16,13], offsets [0,22,41,57], N_TOTAL=70
// W1: (4,4,22,32)  W2/W3: (4,4,32,32)  W4: (4,4,32,22)
#define BLK 256
#define NEDGE_MAX 400000
#define BX 128
#define TSL 24608  // padded per-l table slice: 1024*24 + 32 floats

typedef __attribute__((ext_vector_type(8))) short short8;
typedef __attribute__((ext_vector_type(4))) float f32x4;

union Frag {
  short8 s;
  unsigned int u[4];
};

// ---------------- compaction ----------------

__global__ void k_zero(int* __restrict__ cnt) {
  if (threadIdx.x < 4) cnt[threadIdx.x] = 0;
}

__global__ void __launch_bounds__(BLK) k_compact(const int* __restrict__ spc, int n,
                                                 int* __restrict__ cnt,
                                                 int* __restrict__ perm) {
  __shared__ int wcnt[4][4];
  __shared__ int wbase[4][4];
  const int tid = threadIdx.x;
  const int i = blockIdx.x * BLK + tid;
  const int lane = tid & 63;
  const int w = tid >> 6;
  const int s = (i < n) ? spc[i] : -1;

  int rank = 0;
#pragma unroll
  for (int sp = 0; sp < 4; sp++) {
    unsigned long long m = __ballot(s == sp);
    if (lane == 0) wcnt[w][sp] = __popcll(m);
    if (s == sp) rank = __popcll(m & ((1ULL << lane) - 1ULL));
  }
  __syncthreads();
  if (tid < 4) {
    const int c0 = wcnt[0][tid], c1 = wcnt[1][tid], c2 = wcnt[2][tid], c3 = wcnt[3][tid];
    const int b = atomicAdd(&cnt[tid], c0 + c1 + c2 + c3);
    wbase[0][tid] = b;
    wbase[1][tid] = b + c0;
    wbase[2][tid] = b + c0 + c1;
    wbase[3][tid] = b + c0 + c1 + c2;
  }
  __syncthreads();
  if (s >= 0) perm[s * NEDGE_MAX + wbase[w][s] + rank] = i;
}

// ---------------- padded table staging ----------------

__global__ void __launch_bounds__(256) k_table(const float* __restrict__ tbl,
                                               float* __restrict__ wt) {
  const int t = blockIdx.x * 256 + threadIdx.x;
  if (t < 4 * 1024 * 24) {
    const int l = t / (1024 * 24);
    const int rem = t - l * (1024 * 24);
    const int idx = rem / 24;
    const int j = rem - idx * 24;
    const int off = (l == 0) ? 0 : (l == 1) ? 22 : (l == 2) ? 41 : 57;
    const int nl = (l == 0) ? 22 : (l == 1) ? 19 : (l == 2) ? 16 : 13;
    const float v = (j < nl) ? tbl[idx * 70 + off + j] : 0.f;
    wt[l * TSL + idx * 24 + j] = v;
  }
  if (t < 4 * 32) {
    const int l = t >> 5, j = t & 31;
    wt[l * TSL + 1024 * 24 + j] = 0.f;
  }
}

// ---------------- MFMA compute ----------------

// RNE hi/lo bf16 split of a float pair, packed into one u32 each.
__device__ __forceinline__ void split_pair(float a, float b, unsigned int& hi,
                                           unsigned int& lo) {
  __hip_bfloat162 h2 = __float22bfloat162_rn(float2{a, b});
  const unsigned int h = *reinterpret_cast<unsigned int*>(&h2);
  hi = h;
  const float ra = a - __uint_as_float((h & 0xFFFFu) << 16);
  const float rb = b - __uint_as_float(h & 0xFFFF0000u);
  __hip_bfloat162 l2 = __float22bfloat162_rn(float2{ra, rb});
  lo = *reinterpret_cast<unsigned int*>(&l2);
}

// RNE bf16 pack only (weights: hi term only -> half the register footprint)
__device__ __forceinline__ unsigned int pack_pair(float a, float b) {
  __hip_bfloat162 h2 = __float22bfloat162_rn(float2{a, b});
  return *reinterpret_cast<unsigned int*>(&h2);
}

// D = A_hi * (b_hi + b_lo): 2 MFMAs per quadrant (weight-lo dropped).
__device__ __forceinline__ void do_layer(const Frag* Ah, const Frag& bh,
                                         const Frag& bl, f32x4& d0, f32x4& d1) {
  f32x4 z = {0.f, 0.f, 0.f, 0.f};
  d0 = __builtin_amdgcn_mfma_f32_16x16x32_bf16(Ah[0].s, bl.s, z, 0, 0, 0);
  d0 = __builtin_amdgcn_mfma_f32_16x16x32_bf16(Ah[0].s, bh.s, d0, 0, 0, 0);
  d1 = __builtin_amdgcn_mfma_f32_16x16x32_bf16(Ah[1].s, bl.s, z, 0, 0, 0);
  d1 = __builtin_amdgcn_mfma_f32_16x16x32_bf16(Ah[1].s, bh.s, d1, 0, 0, 0);
}

__device__ __forceinline__ f32x4 silu4(f32x4 v) {
#pragma unroll
  for (int i = 0; i < 4; i++) v[i] = __fdividef(v[i], 1.0f + __expf(-v[i]));
  return v;
}

struct GD {
  f32x4 a0, a1, b0, b1;
  float frac;
  int e;
  int valid;
};

__device__ __forceinline__ GD do_gather(const float* __restrict__ r,
                                        const float* __restrict__ tb,
                                        const int* __restrict__ perm, int sBase,
                                        int ei, int count) {
  GD gd;
  gd.valid = ei < count;
  const int eic = gd.valid ? ei : count - 1;
  gd.e = perm[sBase + eic];
  const float rr = r[gd.e];
  const float xi = rr * (1023.0f / 5.0f);
  int idx = (int)floorf(xi);
  idx = idx < 0 ? 0 : (idx > 1022 ? 1022 : idx);
  gd.frac = xi - (float)idx;
  const float* t0 = tb + idx * 24;
  gd.a0 = *(const f32x4*)(t0);
  gd.a1 = *(const f32x4*)(t0 + 4);
  gd.b0 = *(const f32x4*)(t0 + 24);
  gd.b1 = *(const f32x4*)(t0 + 28);
  return gd;
}

template <int L, int NL, int OFF>
__device__ void body(const float* __restrict__ r, const float* __restrict__ wt,
                     const float* __restrict__ W1, const float* __restrict__ W2,
                     const float* __restrict__ W3, const float* __restrict__ W4,
                     float* __restrict__ out, const int* __restrict__ cnt,
                     const int* __restrict__ perm, float* __restrict__ xpw,
                     int* __restrict__ eidw) {
  const int s = blockIdx.y & 3;
  const int count = cnt[s];
  if (count == 0) return;

  const int lane = threadIdx.x & 63;
  const int w = threadIdx.x >> 6;
  const int c = lane & 15;  // edge column within tile
  const int g = lane >> 4;  // k-group

  const float* __restrict__ w1 = W1 + (size_t)(L * 4 + s) * (22 * 32);
  const float* __restrict__ w2 = W2 + (size_t)(L * 4 + s) * (32 * 32);
  const float* __restrict__ w3 = W3 + (size_t)(L * 4 + s) * (32 * 32);
  const float* __restrict__ w4 = W4 + (size_t)(L * 4 + s) * (32 * 22);

  // A-frags (bf16-RNE hi only): W1 standard k=8g+d; W2/W3/W4 permuted
  // k'(g,d) = (d<4 ? 4g+d : 16+4g+d-4) so the previous layer's D-register
  // layout feeds the next MFMA directly (no transpose, no LDS).
  Frag A1[2], A2[2], A3[2], A4[2];
#pragma unroll
  for (int jt = 0; jt < 2; jt++) {
    const int j = jt * 16 + c;
#pragma unroll
    for (int p = 0; p < 4; p++) {
      const int k0 = 8 * g + 2 * p, k1 = k0 + 1;
      const float a = (k0 < NL) ? w1[k0 * 32 + j] : 0.f;
      const float b = (k1 < NL) ? w1[k1 * 32 + j] : 0.f;
      A1[jt].u[p] = pack_pair(a, b);
      const int kp0 = (p < 2) ? (4 * g + 2 * p) : (16 + 4 * g + 2 * (p - 2));
      const int kp1 = kp0 + 1;
      A2[jt].u[p] = pack_pair(w2[kp0 * 32 + j], w2[kp1 * 32 + j]);
      A3[jt].u[p] = pack_pair(w3[kp0 * 32 + j], w3[kp1 * 32 + j]);
      A4[jt].u[p] = pack_pair((j < NL) ? w4[kp0 * 22 + j] : 0.f,
                              (j < NL) ? w4[kp1 * 22 + j] : 0.f);
    }
  }

  const float* __restrict__ tb = wt + L * TSL + 8 * g;
  const int sBase = s * NEDGE_MAX;
  const int stride = gridDim.x * 64;

  int eb = blockIdx.x * 64 + w * 16;
  GD cur = do_gather(r, tb, perm, sBase, eb + c, count);

  for (; eb < count; eb += stride) {
    GD nxt = do_gather(r, tb, perm, sBase, eb + stride + c, count);

    // ---- layer-1 B frags (standard k = 8g+d; pads are zero) ----
    Frag bh, bl;
    {
      float x[8];
#pragma unroll
      for (int d = 0; d < 4; d++) {
        x[d] = cur.a0[d] + cur.frac * (cur.b0[d] - cur.a0[d]);
        x[d + 4] = cur.a1[d] + cur.frac * (cur.b1[d] - cur.a1[d]);
      }
      split_pair(x[0], x[1], bh.u[0], bl.u[0]);
      split_pair(x[2], x[3], bh.u[1], bl.u[1]);
      split_pair(x[4], x[5], bh.u[2], bl.u[2]);
      split_pair(x[6], x[7], bh.u[3], bl.u[3]);
    }

    f32x4 d0, d1;
    do_layer(A1, bh, bl, d0, d1);

#pragma unroll
    for (int t = 0; t < 3; t++) {
      d0 = silu4(d0);
      d1 = silu4(d1);
      split_pair(d0[0], d0[1], bh.u[0], bl.u[0]);
      split_pair(d0[2], d0[3], bh.u[1], bl.u[1]);
      split_pair(d1[0], d1[1], bh.u[2], bl.u[2]);
      split_pair(d1[2], d1[3], bh.u[3], bl.u[3]);
      if (t == 0) do_layer(A2, bh, bl, d0, d1);
      else if (t == 1) do_layer(A3, bh, bl, d0, d1);
      else do_layer(A4, bh, bl, d0, d1);
    }

    // ---- coalesced epilogue: y^T -> per-wave LDS tile -> row-segment stores ----
    *(f32x4*)(xpw + c * 36 + 4 * g) = d0;       // features 4g..4g+3
    *(f32x4*)(xpw + c * 36 + 16 + 4 * g) = d1;  // features 16+4g..19+4g
    if (g == 0) eidw[c] = cur.valid ? cur.e : -1;
    __asm__ volatile("" ::: "memory");

    constexpr int TOT = 16 * NL;
#pragma unroll
    for (int t = 0; t < (TOT + 63) / 64; t++) {
      const int flat = t * 64 + lane;
      if (flat < TOT) {
        const int row = flat / NL;
        const int f = flat - row * NL;
        const int er = eidw[row];
        if (er >= 0) out[(size_t)er * 70 + OFF + f] = xpw[row * 36 + f];
      }
    }
    __asm__ volatile("" ::: "memory");

    cur = nxt;
  }
}

__global__ void __launch_bounds__(BLK) rb_mfma(const float* __restrict__ r,
                                               const float* __restrict__ wt,
                                               const float* __restrict__ W1,
                                               const float* __restrict__ W2,
                                               const float* __restrict__ W3,
                                               const float* __restrict__ W4,
                                               float* __restrict__ out,
                                               const int* __restrict__ cnt,
                                               const int* __restrict__ perm) {
  __shared__ float xpose[4][16 * 36];
  __shared__ int eidt[4][16];
  const int w = threadIdx.x >> 6;
  float* xpw = &xpose[w][0];
  int* eidw = &eidt[w][0];
  switch (blockIdx.y >> 2) {
    case 0: body<0, 22, 0>(r, wt, W1, W2, W3, W4, out, cnt, perm, xpw, eidw); break;
    case 1: body<1, 19, 22>(r, wt, W1, W2, W3, W4, out, cnt, perm, xpw, eidw); break;
    case 2: body<2, 16, 41>(r, wt, W1, W2, W3, W4, out, cnt, perm, xpw, eidw); break;
    default: body<3, 13, 57>(r, wt, W1, W2, W3, W4, out, cnt, perm, xpw, eidw); break;
  }
}

extern "C" void kernel_launch(void* const* d_in, const int* in_sizes, int n_in,
                              void* d_out, int out_size, void* d_ws, size_t ws_size,
                              hipStream_t stream) {
  const float* r = (const float*)d_in[0];
  const int* spc = (const int*)d_in[1];
  const float* tbl = (const float*)d_in[2];
  const float* W1 = (const float*)d_in[3];
  const float* W2 = (const float*)d_in[4];
  const float* W3 = (const float*)d_in[5];
  const float* W4 = (const float*)d_in[6];
  float* out = (float*)d_out;
  const int n = in_sizes[0];

  int* cnt = (int*)d_ws;
  int* perm = (int*)d_ws + 64;
  float* wtbl = (float*)((int*)d_ws + 64 + 4 * NEDGE_MAX);

  hipLaunchKernelGGL(k_zero, dim3(1), dim3(64), 0, stream, cnt);

  const int nb = (n + BLK - 1) / BLK;
  hipLaunchKernelGGL(k_compact, dim3(nb), dim3(BLK), 0, stream, spc, n, cnt, perm);

  hipLaunchKernelGGL(k_table, dim3((4 * 1024 * 24 + 255) / 256), dim3(256), 0,
                     stream, tbl, wtbl);

  hipLaunchKernelGGL(rb_mfma, dim3(BX, 16), dim3(BLK), 0, stream, r, wtbl, W1, W2,
                     W3, W4, out, cnt, perm);
}

// Round 8
// 145.063 us; speedup vs baseline: 1.1003x; 1.1003x over previous
//
#include <hip/hip_runtime.h>
#include <hip/hip_bf16.h>
#include <math.h>

// N_MAX_L = [22,19,16,13], offsets [0,22,41,57], N_TOTAL=70
// W1: (4,4,22,32)  W2/W3: (4,4,32,32)  W4: (4,4,32,22)
#define BLK 256
#define NEDGE_MAX 400000
#define BX 128
#define TSL 24608  // padded per-l table slice: 1024*24 + 32 floats

typedef __attribute__((ext_vector_type(8))) short short8;
typedef __attribute__((ext_vector_type(4))) float f32x4;

union Frag {
  short8 s;
  unsigned int u[4];
};

// ---------------- compaction (also writes compacted r) ----------------

__global__ void k_zero(int* __restrict__ cnt) {
  if (threadIdx.x < 4) cnt[threadIdx.x] = 0;
}

__global__ void __launch_bounds__(BLK) k_compact(const int* __restrict__ spc,
                                                 const float* __restrict__ r, int n,
                                                 int* __restrict__ cnt,
                                                 int* __restrict__ perm,
                                                 float* __restrict__ rs) {
  __shared__ int wcnt[4][4];
  __shared__ int wbase[4][4];
  const int tid = threadIdx.x;
  const int i = blockIdx.x * BLK + tid;
  const int lane = tid & 63;
  const int w = tid >> 6;
  const int s = (i < n) ? spc[i] : -1;
  const float rv = (i < n) ? r[i] : 0.f;

  int rank = 0;
#pragma unroll
  for (int sp = 0; sp < 4; sp++) {
    unsigned long long m = __ballot(s == sp);
    if (lane == 0) wcnt[w][sp] = __popcll(m);
    if (s == sp) rank = __popcll(m & ((1ULL << lane) - 1ULL));
  }
  __syncthreads();
  if (tid < 4) {
    const int c0 = wcnt[0][tid], c1 = wcnt[1][tid], c2 = wcnt[2][tid], c3 = wcnt[3][tid];
    const int b = atomicAdd(&cnt[tid], c0 + c1 + c2 + c3);
    wbase[0][tid] = b;
    wbase[1][tid] = b + c0;
    wbase[2][tid] = b + c0 + c1;
    wbase[3][tid] = b + c0 + c1 + c2;
  }
  __syncthreads();
  if (s >= 0) {
    const int pos = wbase[w][s] + rank;
    perm[s * NEDGE_MAX + pos] = i;
    rs[s * NEDGE_MAX + pos] = rv;
  }
}

// ---------------- padded table staging ----------------

__global__ void __launch_bounds__(256) k_table(const float* __restrict__ tbl,
                                               float* __restrict__ wt) {
  const int t = blockIdx.x * 256 + threadIdx.x;
  if (t < 4 * 1024 * 24) {
    const int l = t / (1024 * 24);
    const int rem = t - l * (1024 * 24);
    const int idx = rem / 24;
    const int j = rem - idx * 24;
    const int off = (l == 0) ? 0 : (l == 1) ? 22 : (l == 2) ? 41 : 57;
    const int nl = (l == 0) ? 22 : (l == 1) ? 19 : (l == 2) ? 16 : 13;
    const float v = (j < nl) ? tbl[idx * 70 + off + j] : 0.f;
    wt[l * TSL + idx * 24 + j] = v;
  }
  if (t < 4 * 32) {
    const int l = t >> 5, j = t & 31;
    wt[l * TSL + 1024 * 24 + j] = 0.f;
  }
}

// ---------------- MFMA compute ----------------

// RNE hi/lo bf16 split of a float pair, packed into one u32 each.
__device__ __forceinline__ void split_pair(float a, float b, unsigned int& hi,
                                           unsigned int& lo) {
  __hip_bfloat162 h2 = __float22bfloat162_rn(float2{a, b});
  const unsigned int h = *reinterpret_cast<unsigned int*>(&h2);
  hi = h;
  const float ra = a - __uint_as_float((h & 0xFFFFu) << 16);
  const float rb = b - __uint_as_float(h & 0xFFFF0000u);
  __hip_bfloat162 l2 = __float22bfloat162_rn(float2{ra, rb});
  lo = *reinterpret_cast<unsigned int*>(&l2);
}

// RNE bf16 pack only
__device__ __forceinline__ unsigned int pack_pair(float a, float b) {
  __hip_bfloat162 h2 = __float22bfloat162_rn(float2{a, b});
  return *reinterpret_cast<unsigned int*>(&h2);
}

// layer with activation hi+lo compensation (used for layer 1)
__device__ __forceinline__ void layer_hl(const Frag* A, const Frag& bh,
                                         const Frag& bl, f32x4& d0, f32x4& d1) {
  f32x4 z = {0.f, 0.f, 0.f, 0.f};
  d0 = __builtin_amdgcn_mfma_f32_16x16x32_bf16(A[0].s, bl.s, z, 0, 0, 0);
  d0 = __builtin_amdgcn_mfma_f32_16x16x32_bf16(A[0].s, bh.s, d0, 0, 0, 0);
  d1 = __builtin_amdgcn_mfma_f32_16x16x32_bf16(A[1].s, bl.s, z, 0, 0, 0);
  d1 = __builtin_amdgcn_mfma_f32_16x16x32_bf16(A[1].s, bh.s, d1, 0, 0, 0);
}

// pure-bf16 layer (layers 2-4)
__device__ __forceinline__ void layer_h(const Frag* A, const Frag& bh, f32x4& d0,
                                        f32x4& d1) {
  f32x4 z = {0.f, 0.f, 0.f, 0.f};
  d0 = __builtin_amdgcn_mfma_f32_16x16x32_bf16(A[0].s, bh.s, z, 0, 0, 0);
  d1 = __builtin_amdgcn_mfma_f32_16x16x32_bf16(A[1].s, bh.s, z, 0, 0, 0);
}

__device__ __forceinline__ f32x4 silu4(f32x4 v) {
#pragma unroll
  for (int i = 0; i < 4; i++) v[i] = __fdividef(v[i], 1.0f + __expf(-v[i]));
  return v;
}

struct GD {
  f32x4 a0, a1, b0, b1;
  float frac;
  int e;
  int valid;
};

// 1-hop gather: coalesced rs stream -> table (L2). perm feeds epilogue only.
__device__ __forceinline__ GD do_gather(const float* __restrict__ rs,
                                        const float* __restrict__ tb,
                                        const int* __restrict__ perm, int sBase,
                                        int ei, int count) {
  GD gd;
  gd.valid = ei < count;
  const int eic = gd.valid ? ei : 0;
  gd.e = perm[sBase + eic];        // independent load (store address)
  const float rr = rs[sBase + eic];  // coalesced stream
  const float xi = rr * (1023.0f / 5.0f);
  int idx = (int)floorf(xi);
  idx = idx < 0 ? 0 : (idx > 1022 ? 1022 : idx);
  gd.frac = xi - (float)idx;
  const float* t0 = tb + idx * 24;
  gd.a0 = *(const f32x4*)(t0);
  gd.a1 = *(const f32x4*)(t0 + 4);
  gd.b0 = *(const f32x4*)(t0 + 24);
  gd.b1 = *(const f32x4*)(t0 + 28);
  return gd;
}

template <int L, int NL, int OFF>
__device__ void body(const float* __restrict__ rs, const float* __restrict__ wt,
                     const float* __restrict__ W1, const float* __restrict__ W2,
                     const float* __restrict__ W3, const float* __restrict__ W4,
                     float* __restrict__ out, const int* __restrict__ cnt,
                     const int* __restrict__ perm, float* __restrict__ xpw,
                     int* __restrict__ eidw) {
  const int s = blockIdx.y & 3;
  const int count = cnt[s];
  if (count == 0) return;

  const int lane = threadIdx.x & 63;
  const int w = threadIdx.x >> 6;
  const int c = lane & 15;  // edge column within tile
  const int g = lane >> 4;  // k-group

  const float* __restrict__ w1 = W1 + (size_t)(L * 4 + s) * (22 * 32);
  const float* __restrict__ w2 = W2 + (size_t)(L * 4 + s) * (32 * 32);
  const float* __restrict__ w3 = W3 + (size_t)(L * 4 + s) * (32 * 32);
  const float* __restrict__ w4 = W4 + (size_t)(L * 4 + s) * (32 * 22);

  // A-frags (bf16-RNE): W1 standard k=8g+d; W2/W3/W4 permuted
  // k'(g,d) = (d<4 ? 4g+d : 16+4g+d-4) so the previous layer's D-register
  // layout feeds the next MFMA directly (no transpose, no LDS).
  Frag A1[2], A2[2], A3[2], A4[2];
#pragma unroll
  for (int jt = 0; jt < 2; jt++) {
    const int j = jt * 16 + c;
#pragma unroll
    for (int p = 0; p < 4; p++) {
      const int k0 = 8 * g + 2 * p, k1 = k0 + 1;
      const float a = (k0 < NL) ? w1[k0 * 32 + j] : 0.f;
      const float b = (k1 < NL) ? w1[k1 * 32 + j] : 0.f;
      A1[jt].u[p] = pack_pair(a, b);
      const int kp0 = (p < 2) ? (4 * g + 2 * p) : (16 + 4 * g + 2 * (p - 2));
      const int kp1 = kp0 + 1;
      A2[jt].u[p] = pack_pair(w2[kp0 * 32 + j], w2[kp1 * 32 + j]);
      A3[jt].u[p] = pack_pair(w3[kp0 * 32 + j], w3[kp1 * 32 + j]);
      A4[jt].u[p] = pack_pair((j < NL) ? w4[kp0 * 22 + j] : 0.f,
                              (j < NL) ? w4[kp1 * 22 + j] : 0.f);
    }
  }

  const float* __restrict__ tb = wt + L * TSL + 8 * g;
  const int sBase = s * NEDGE_MAX;
  const int stride = gridDim.x * 64;

  int eb = blockIdx.x * 64 + w * 16;
  GD cur = do_gather(rs, tb, perm, sBase, eb + c, count);

  for (; eb < count; eb += stride) {
    GD nxt = do_gather(rs, tb, perm, sBase, eb + stride + c, count);

    // ---- layer-1 B frags (standard k = 8g+d; pads are zero), hi/lo split ----
    Frag bh, bl;
    {
      float x[8];
#pragma unroll
      for (int d = 0; d < 4; d++) {
        x[d] = cur.a0[d] + cur.frac * (cur.b0[d] - cur.a0[d]);
        x[d + 4] = cur.a1[d] + cur.frac * (cur.b1[d] - cur.a1[d]);
      }
      split_pair(x[0], x[1], bh.u[0], bl.u[0]);
      split_pair(x[2], x[3], bh.u[1], bl.u[1]);
      split_pair(x[4], x[5], bh.u[2], bl.u[2]);
      split_pair(x[6], x[7], bh.u[3], bl.u[3]);
    }

    f32x4 d0, d1;
    layer_hl(A1, bh, bl, d0, d1);

    // ---- transitions: silu -> pure-bf16 repack (k'-mapping) -> next layer ----
#pragma unroll
    for (int t = 0; t < 3; t++) {
      d0 = silu4(d0);
      d1 = silu4(d1);
      bh.u[0] = pack_pair(d0[0], d0[1]);
      bh.u[1] = pack_pair(d0[2], d0[3]);
      bh.u[2] = pack_pair(d1[0], d1[1]);
      bh.u[3] = pack_pair(d1[2], d1[3]);
      if (t == 0) layer_h(A2, bh, d0, d1);
      else if (t == 1) layer_h(A3, bh, d0, d1);
      else layer_h(A4, bh, d0, d1);
    }

    // ---- coalesced epilogue: y^T -> per-wave LDS tile -> row-segment stores ----
    *(f32x4*)(xpw + c * 36 + 4 * g) = d0;       // features 4g..4g+3
    *(f32x4*)(xpw + c * 36 + 16 + 4 * g) = d1;  // features 16+4g..19+4g
    if (g == 0) eidw[c] = cur.valid ? cur.e : -1;
    __asm__ volatile("" ::: "memory");

    constexpr int TOT = 16 * NL;
#pragma unroll
    for (int t = 0; t < (TOT + 63) / 64; t++) {
      const int flat = t * 64 + lane;
      if (flat < TOT) {
        const int row = flat / NL;
        const int f = flat - row * NL;
        const int er = eidw[row];
        if (er >= 0) out[(size_t)er * 70 + OFF + f] = xpw[row * 36 + f];
      }
    }
    __asm__ volatile("" ::: "memory");

    cur = nxt;
  }
}

__global__ void __launch_bounds__(BLK) rb_mfma(const float* __restrict__ rs,
                                               const float* __restrict__ wt,
                                               const float* __restrict__ W1,
                                               const float* __restrict__ W2,
                                               const float* __restrict__ W3,
                                               const float* __restrict__ W4,
                                               float* __restrict__ out,
                                               const int* __restrict__ cnt,
                                               const int* __restrict__ perm) {
  __shared__ float xpose[4][16 * 36];
  __shared__ int eidt[4][16];
  const int w = threadIdx.x >> 6;
  float* xpw = &xpose[w][0];
  int* eidw = &eidt[w][0];
  switch (blockIdx.y >> 2) {
    case 0: body<0, 22, 0>(rs, wt, W1, W2, W3, W4, out, cnt, perm, xpw, eidw); break;
    case 1: body<1, 19, 22>(rs, wt, W1, W2, W3, W4, out, cnt, perm, xpw, eidw); break;
    case 2: body<2, 16, 41>(rs, wt, W1, W2, W3, W4, out, cnt, perm, xpw, eidw); break;
    default: body<3, 13, 57>(rs, wt, W1, W2, W3, W4, out, cnt, perm, xpw, eidw); break;
  }
}

extern "C" void kernel_launch(void* const* d_in, const int* in_sizes, int n_in,
                              void* d_out, int out_size, void* d_ws, size_t ws_size,
                              hipStream_t stream) {
  const float* r = (const float*)d_in[0];
  const int* spc = (const int*)d_in[1];
  const float* tbl = (const float*)d_in[2];
  const float* W1 = (const float*)d_in[3];
  const float* W2 = (const float*)d_in[4];
  const float* W3 = (const float*)d_in[5];
  const float* W4 = (const float*)d_in[6];
  float* out = (float*)d_out;
  const int n = in_sizes[0];

  int* cnt = (int*)d_ws;                       // 4 ints (+pad to 64)
  int* perm = (int*)d_ws + 64;                 // 4 * NEDGE_MAX ints
  float* rs = (float*)((int*)d_ws + 64 + 4 * NEDGE_MAX);   // 4 * NEDGE_MAX floats
  float* wtbl = rs + 4 * NEDGE_MAX;            // 4 * TSL floats

  hipLaunchKernelGGL(k_zero, dim3(1), dim3(64), 0, stream, cnt);

  const int nb = (n + BLK - 1) / BLK;
  hipLaunchKernelGGL(k_compact, dim3(nb), dim3(BLK), 0, stream, spc, r, n, cnt,
                     perm, rs);

  hipLaunchKernelGGL(k_table, dim3((4 * 1024 * 24 + 255) / 256), dim3(256), 0,
                     stream, tbl, wtbl);

  hipLaunchKernelGGL(rb_mfma, dim3(BX, 16), dim3(BLK), 0, stream, rs, wtbl, W1, W2,
                     W3, W4, out, cnt, perm);
}